// Round 5
// baseline (33073.843 us; speedup 1.0000x reference)
//
#include <hip/hip_runtime.h>
#include <hip/hip_bf16.h>

typedef short  short8  __attribute__((ext_vector_type(8)));
typedef float  float4v __attribute__((ext_vector_type(4)));
typedef unsigned long long u64;

#define NSTEPS 60
#define ROWS   64
#define NWG    32   // 2048 / ROWS

constexpr double Hd = 1.0 / 60.0;
__device__ const float HACO[6][5] = {
  {0.f,0.f,0.f,0.f,0.f},
  {(float)(Hd*0.161), 0.f,0.f,0.f,0.f},
  {(float)(Hd*-0.008480655492356989), (float)(Hd*0.335480655492357), 0.f,0.f,0.f},
  {(float)(Hd*2.8971530571054935), (float)(Hd*-6.359448489975075), (float)(Hd*4.3622954328695815), 0.f,0.f},
  {(float)(Hd*5.325864828439257), (float)(Hd*-11.748883564062828), (float)(Hd*7.4955393428898365), (float)(Hd*-0.09249506636175525), 0.f},
  {(float)(Hd*5.86145544294642), (float)(Hd*-12.92096931784711), (float)(Hd*8.159367898576159), (float)(Hd*-0.071584973281401), (float)(Hd*-0.028269050394068383)}
};
__device__ const float HBCO[6] = {
  (float)(Hd*0.09646076681806523), (float)(Hd*0.01), (float)(Hd*0.4798896504144996),
  (float)(Hd*1.379008574103742), (float)(Hd*-3.290069515436081), (float)(Hd*2.324710524099774)
};

__device__ __forceinline__ unsigned short f2bf(float f) {
    union { float f; unsigned u; } v; v.f = f;
    unsigned r = v.u + 0x7fffu + ((v.u >> 16) & 1u);   // RNE
    return (unsigned short)(r >> 16);
}
__device__ __forceinline__ unsigned pack2(float a, float b) {
    return (unsigned)f2bf(a) | ((unsigned)f2bf(b) << 16);
}
__device__ __forceinline__ float bfl(unsigned u) { union { unsigned v; float f; } x; x.v = u << 16; return x.f; }
__device__ __forceinline__ float bfh(unsigned u) { union { unsigned v; float f; } x; x.v = u & 0xffff0000u; return x.f; }

// ws layout (1-KB fragment-linear blocks; lane l of block (nt,ks) holds
// W[n=nt*16+(l&15)][k=ks*32+(l>>4)*8 .. +8] as bf16 short8):
//   blk [０,256)   W1y (K=256, cols 0..255 of W1)
//   blk [256,512)  W1u (K=256, cols 256..511 of W1)
//   blk [512,1024) W2  (K=512)
//   blk [1024,1280) W3 (K=512)
// then per-WG k-buffers: 6 stages × 64 tiles × 512 B = 192 KB each.
__global__ void wconv(const float* __restrict__ W1, const float* __restrict__ W2,
                      const float* __restrict__ W3, unsigned short* __restrict__ ws) {
    int g = blockIdx.x * blockDim.x + threadIdx.x;    // 0..81919
    int blk = g >> 6, l = g & 63;
    const float* src;
    if (blk < 512) {                  // W1y / W1u
        int half = blk >> 8;          // 0=W1y, 1=W1u
        int b = blk & 255; int nt = b >> 3, ks = b & 7;
        int n = nt * 16 + (l & 15), k = ks * 32 + (l >> 4) * 8 + half * 256;
        src = W1 + n * 512 + k;
    } else if (blk < 1024) {          // W2
        int b = blk - 512; int nt = b >> 4, ks = b & 15;
        int n = nt * 16 + (l & 15), k = ks * 32 + (l >> 4) * 8;
        src = W2 + n * 512 + k;
    } else {                          // W3
        int b = blk - 1024; int nt = b >> 4, ks = b & 15;
        int n = nt * 16 + (l & 15), k = ks * 32 + (l >> 4) * 8;
        src = W3 + n * 512 + k;
    }
    short8 v;
#pragma unroll
    for (int j = 0; j < 8; ++j) v[j] = (short)f2bf(src[j]);
    *(((short8*)ws) + g) = v;
}

// A-fragment load: two ds_read_b64 with 4-bit granule-XOR swizzle (4-way max conflict).
// Logical layout: [row][RG ulong-granules]; granule g stored at g ^ (row&15).
template<int RG>
__device__ __forceinline__ short8 lda(const unsigned short* h, int row, int ks, int l4) {
    const u64* p = (const u64*)h;
    const int base = row * RG, s = row & 15;
    const int g0 = ks * 8 + l4 * 2;
    union { u64 q[2]; short8 v; } t;
    t.q[0] = p[base + (g0 ^ s)];
    t.q[1] = p[base + ((g0 + 1) ^ s)];
    return t.v;
}
// bf16 scalar store into the same swizzled layout (RG = ulong-granules per row).
template<int RG>
__device__ __forceinline__ void sth(unsigned short* h, int row, int n, unsigned short v) {
    h[row * (RG * 4) + ((((n >> 2) ^ (row & 15))) << 2) + (n & 3)] = v;
}

// One WG = 64 rows, 8 waves, full 60-step Tsit5. k1..k6 in per-WG global frag-buffers.
__global__ void __launch_bounds__(512, 2) odeint(
        const float* __restrict__ x0, const float* __restrict__ uf,
        const float* __restrict__ b1g, const float* __restrict__ b2g,
        const float* __restrict__ b3g, unsigned short* __restrict__ ws,
        float* __restrict__ out) {
    __shared__ __align__(16) unsigned short h1[64 * 512];
    __shared__ __align__(16) unsigned short h2[64 * 512];
    unsigned short* xb = h2;                    // overlay: 64x256 shorts (32 KB)

    const int tid = threadIdx.x, w = tid >> 6, lane = tid & 63;
    const int l15 = lane & 15, l4 = lane >> 4;
    const int r0 = blockIdx.x * ROWS;
    const bool forced = (r0 < 1024);

    const short8* ws8 = (const short8*)ws;
    const short8* wby1 = ws8;                    // W1y
    const short8* wbu  = ws8 + 256 * 64;         // W1u
    const short8* wb2  = ws8 + 512 * 64;         // W2
    const short8* wb3  = ws8 + 1024 * 64;        // W3
    u64* kb = (u64*)(ws + 655360) + (size_t)blockIdx.x * (6 * 64 * 64) + lane;

    // ---- biases to registers ----
    float b1r[4], b2r[4], b3r[2];
#pragma unroll
    for (int j = 0; j < 4; ++j) { b1r[j] = b1g[(w*4+j)*16 + l15]; b2r[j] = b2g[(w*4+j)*16 + l15]; }
#pragma unroll
    for (int nt = 0; nt < 2; ++nt) b3r[nt] = b3g[(w*2+nt)*16 + l15];

    // ---- stage u (bf16, swizzled) into xb ----
    {
        u64* xq = (u64*)xb;
        for (int i = tid; i < 64 * 64; i += 512) {
            int row = i >> 6, g = i & 63;
            union { u64 q; unsigned short s[4]; } t;
            t.q = 0;
            if (forced) {
                const float* up = uf + (size_t)(r0 + row) * 256 + g * 4;
#pragma unroll
                for (int e = 0; e < 4; ++e) t.s[e] = f2bf(up[e]);
            }
            xq[row * 64 + (g ^ (row & 15))] = t.q;
        }
    }
    __syncthreads();

    // ---- c1 = u @ W1u^T + b1 (one-time MFMA), packed bf16 in regs ----
    unsigned c1p[4][4][2];
    {
        float4v acc[4][4];
#pragma unroll
        for (int j = 0; j < 4; ++j)
#pragma unroll
        for (int mt = 0; mt < 4; ++mt) acc[j][mt] = (float4v){0.f,0.f,0.f,0.f};
        short8 bc[4];
#pragma unroll
        for (int j = 0; j < 4; ++j) bc[j] = wbu[(((w*4+j)*8) << 6) + lane];
#pragma unroll
        for (int ks = 0; ks < 8; ++ks) {
            short8 a[4];
#pragma unroll
            for (int mt = 0; mt < 4; ++mt) a[mt] = lda<64>(xb, mt*16 + l15, ks, l4);
            short8 bn[4];
#pragma unroll
            for (int j = 0; j < 4; ++j) bn[j] = (ks < 7) ? wbu[(((w*4+j)*8 + ks+1) << 6) + lane] : bc[j];
#pragma unroll
            for (int j = 0; j < 4; ++j)
#pragma unroll
            for (int mt = 0; mt < 4; ++mt)
                acc[j][mt] = __builtin_amdgcn_mfma_f32_16x16x32_bf16(a[mt], bc[j], acc[j][mt], 0, 0, 0);
#pragma unroll
            for (int j = 0; j < 4; ++j) bc[j] = bn[j];
        }
#pragma unroll
        for (int j = 0; j < 4; ++j)
#pragma unroll
        for (int mt = 0; mt < 4; ++mt) {
            c1p[j][mt][0] = pack2(acc[j][mt][0] + b1r[j], acc[j][mt][1] + b1r[j]);
            c1p[j][mt][1] = pack2(acc[j][mt][2] + b1r[j], acc[j][mt][3] + b1r[j]);
        }
    }
    __syncthreads();                             // xb readers done before stage-x rewrites

    // ---- y init (C/D fragment ownership: row = mt*16 + l4*4 + r, n = (w*2+nt)*16 + l15) ----
    float y[2][4][4];
#pragma unroll
    for (int nt = 0; nt < 2; ++nt)
#pragma unroll
    for (int mt = 0; mt < 4; ++mt)
#pragma unroll
    for (int r = 0; r < 4; ++r)
        y[nt][mt][r] = x0[(size_t)((r0 + mt*16 + l4*4 + r) & 1023) * 256 + (w*2+nt)*16 + l15];

    for (int step = 0; step < NSTEPS; ++step) {
        for (int S = 0; S < 6; ++S) {
            // ---- stage-x: x = y + sum_{j<S} HACO[S][j] * k_j  -> xb ----
            const float* co = HACO[S];
#pragma unroll
            for (int nt = 0; nt < 2; ++nt)
#pragma unroll
            for (int mt = 0; mt < 4; ++mt) {
                const int tg = (w*2+nt)*4 + mt;
                float xr0 = y[nt][mt][0], xr1 = y[nt][mt][1], xr2 = y[nt][mt][2], xr3 = y[nt][mt][3];
                for (int j = 0; j < S; ++j) {
                    u64 kq = kb[(j*64 + tg) << 6];
                    float c = co[j];
                    xr0 += c * bfl((unsigned)kq);
                    xr1 += c * bfh((unsigned)kq);
                    xr2 += c * bfl((unsigned)(kq >> 32));
                    xr3 += c * bfh((unsigned)(kq >> 32));
                }
                const int n = (w*2+nt)*16 + l15;
                sth<64>(xb, mt*16 + l4*4 + 0, n, f2bf(xr0));
                sth<64>(xb, mt*16 + l4*4 + 1, n, f2bf(xr1));
                sth<64>(xb, mt*16 + l4*4 + 2, n, f2bf(xr2));
                sth<64>(xb, mt*16 + l4*4 + 3, n, f2bf(xr3));
            }
            __syncthreads();                     // B1: xb ready
            // ---- L1: xb (K=256) @ W1y -> h1 (+c1, relu) ----
            {
                float4v acc[4][4];
#pragma unroll
                for (int j = 0; j < 4; ++j)
#pragma unroll
                for (int mt = 0; mt < 4; ++mt) acc[j][mt] = (float4v){0.f,0.f,0.f,0.f};
                short8 bc[4];
#pragma unroll
                for (int j = 0; j < 4; ++j) bc[j] = wby1[(((w*4+j)*8) << 6) + lane];
#pragma unroll
                for (int ks = 0; ks < 8; ++ks) {
                    short8 a[4];
#pragma unroll
                    for (int mt = 0; mt < 4; ++mt) a[mt] = lda<64>(xb, mt*16 + l15, ks, l4);
                    short8 bn[4];
#pragma unroll
                    for (int j = 0; j < 4; ++j) bn[j] = (ks < 7) ? wby1[(((w*4+j)*8 + ks+1) << 6) + lane] : bc[j];
#pragma unroll
                    for (int j = 0; j < 4; ++j)
#pragma unroll
                    for (int mt = 0; mt < 4; ++mt)
                        acc[j][mt] = __builtin_amdgcn_mfma_f32_16x16x32_bf16(a[mt], bc[j], acc[j][mt], 0, 0, 0);
#pragma unroll
                    for (int j = 0; j < 4; ++j) bc[j] = bn[j];
                }
#pragma unroll
                for (int j = 0; j < 4; ++j)
#pragma unroll
                for (int mt = 0; mt < 4; ++mt) {
                    const int n = (w*4+j)*16 + l15;
                    float v0 = acc[j][mt][0] + bfl(c1p[j][mt][0]);
                    float v1 = acc[j][mt][1] + bfh(c1p[j][mt][0]);
                    float v2 = acc[j][mt][2] + bfl(c1p[j][mt][1]);
                    float v3 = acc[j][mt][3] + bfh(c1p[j][mt][1]);
                    sth<128>(h1, mt*16 + l4*4 + 0, n, f2bf(fmaxf(v0, 0.f)));
                    sth<128>(h1, mt*16 + l4*4 + 1, n, f2bf(fmaxf(v1, 0.f)));
                    sth<128>(h1, mt*16 + l4*4 + 2, n, f2bf(fmaxf(v2, 0.f)));
                    sth<128>(h1, mt*16 + l4*4 + 3, n, f2bf(fmaxf(v3, 0.f)));
                }
            }
            __syncthreads();                     // B2: h1 ready (xb fully consumed)
            // ---- L2: h1 (K=512) @ W2 -> h2 (+b2, relu) ----
            {
                float4v acc[4][4];
#pragma unroll
                for (int j = 0; j < 4; ++j)
#pragma unroll
                for (int mt = 0; mt < 4; ++mt) acc[j][mt] = (float4v){0.f,0.f,0.f,0.f};
                short8 bc[4];
#pragma unroll
                for (int j = 0; j < 4; ++j) bc[j] = wb2[(((w*4+j)*16) << 6) + lane];
#pragma unroll
                for (int ks = 0; ks < 16; ++ks) {
                    short8 a[4];
#pragma unroll
                    for (int mt = 0; mt < 4; ++mt) a[mt] = lda<128>(h1, mt*16 + l15, ks, l4);
                    short8 bn[4];
#pragma unroll
                    for (int j = 0; j < 4; ++j) bn[j] = (ks < 15) ? wb2[(((w*4+j)*16 + ks+1) << 6) + lane] : bc[j];
#pragma unroll
                    for (int j = 0; j < 4; ++j)
#pragma unroll
                    for (int mt = 0; mt < 4; ++mt)
                        acc[j][mt] = __builtin_amdgcn_mfma_f32_16x16x32_bf16(a[mt], bc[j], acc[j][mt], 0, 0, 0);
#pragma unroll
                    for (int j = 0; j < 4; ++j) bc[j] = bn[j];
                }
#pragma unroll
                for (int j = 0; j < 4; ++j)
#pragma unroll
                for (int mt = 0; mt < 4; ++mt) {
                    const int n = (w*4+j)*16 + l15;
                    sth<128>(h2, mt*16 + l4*4 + 0, n, f2bf(fmaxf(acc[j][mt][0] + b2r[j], 0.f)));
                    sth<128>(h2, mt*16 + l4*4 + 1, n, f2bf(fmaxf(acc[j][mt][1] + b2r[j], 0.f)));
                    sth<128>(h2, mt*16 + l4*4 + 2, n, f2bf(fmaxf(acc[j][mt][2] + b2r[j], 0.f)));
                    sth<128>(h2, mt*16 + l4*4 + 3, n, f2bf(fmaxf(acc[j][mt][3] + b2r[j], 0.f)));
                }
            }
            __syncthreads();                     // B3: h2 ready
            // ---- L3: h2 (K=512) @ W3 -> k_S (global frag-buffer, bf16) ----
            {
                float4v acc[2][4];
#pragma unroll
                for (int nt = 0; nt < 2; ++nt)
#pragma unroll
                for (int mt = 0; mt < 4; ++mt) acc[nt][mt] = (float4v){0.f,0.f,0.f,0.f};
                short8 bc[2];
#pragma unroll
                for (int nt = 0; nt < 2; ++nt) bc[nt] = wb3[(((w*2+nt)*16) << 6) + lane];
#pragma unroll
                for (int ks = 0; ks < 16; ++ks) {
                    short8 a[4];
#pragma unroll
                    for (int mt = 0; mt < 4; ++mt) a[mt] = lda<128>(h2, mt*16 + l15, ks, l4);
                    short8 bn[2];
#pragma unroll
                    for (int nt = 0; nt < 2; ++nt) bn[nt] = (ks < 15) ? wb3[(((w*2+nt)*16 + ks+1) << 6) + lane] : bc[nt];
#pragma unroll
                    for (int nt = 0; nt < 2; ++nt)
#pragma unroll
                    for (int mt = 0; mt < 4; ++mt)
                        acc[nt][mt] = __builtin_amdgcn_mfma_f32_16x16x32_bf16(a[mt], bc[nt], acc[nt][mt], 0, 0, 0);
#pragma unroll
                    for (int nt = 0; nt < 2; ++nt) bc[nt] = bn[nt];
                }
#pragma unroll
                for (int nt = 0; nt < 2; ++nt)
#pragma unroll
                for (int mt = 0; mt < 4; ++mt) {
                    const int tg = (w*2+nt)*4 + mt;
                    u64 q = (u64)pack2(acc[nt][mt][0] + b3r[nt], acc[nt][mt][1] + b3r[nt])
                          | ((u64)pack2(acc[nt][mt][2] + b3r[nt], acc[nt][mt][3] + b3r[nt]) << 32);
                    kb[(S*64 + tg) << 6] = q;
                }
            }
            __syncthreads();                     // B4: h2 reads done before next stage-x xb write
        }
        // ---- y update: y += sum_j HBCO[j] * k_j (own-lane k frags) ----
#pragma unroll
        for (int nt = 0; nt < 2; ++nt)
#pragma unroll
        for (int mt = 0; mt < 4; ++mt) {
            const int tg = (w*2+nt)*4 + mt;
#pragma unroll
            for (int j = 0; j < 6; ++j) {
                u64 kq = kb[(j*64 + tg) << 6];
                float c = HBCO[j];
                y[nt][mt][0] += c * bfl((unsigned)kq);
                y[nt][mt][1] += c * bfh((unsigned)kq);
                y[nt][mt][2] += c * bfl((unsigned)(kq >> 32));
                y[nt][mt][3] += c * bfh((unsigned)(kq >> 32));
            }
        }
    }

#pragma unroll
    for (int nt = 0; nt < 2; ++nt)
#pragma unroll
    for (int mt = 0; mt < 4; ++mt)
#pragma unroll
    for (int r = 0; r < 4; ++r)
        out[(size_t)(r0 + mt*16 + l4*4 + r) * 256 + (w*2+nt)*16 + l15] = y[nt][mt][r];
}

extern "C" void kernel_launch(void* const* d_in, const int* in_sizes, int n_in,
                              void* d_out, int out_size, void* d_ws, size_t ws_size,
                              hipStream_t stream) {
    const float* x0 = (const float*)d_in[0];
    const float* uf = (const float*)d_in[1];
    const float* W1 = (const float*)d_in[2];
    const float* b1 = (const float*)d_in[3];
    const float* W2 = (const float*)d_in[4];
    const float* b2 = (const float*)d_in[5];
    const float* W3 = (const float*)d_in[6];
    const float* b3 = (const float*)d_in[7];
    unsigned short* ws = (unsigned short*)d_ws;   // 1.25 MB weights + 6 MB k-buffers

    wconv<<<160, 512, 0, stream>>>(W1, W2, W3, ws);
    odeint<<<NWG, 512, 0, stream>>>(x0, uf, b1, b2, b3, ws, (float*)d_out);
}

// Round 7
// 20604.259 us; speedup vs baseline: 1.6052x; 1.6052x over previous
//
#include <hip/hip_runtime.h>
#include <hip/hip_bf16.h>

typedef short  short8  __attribute__((ext_vector_type(8)));
typedef float  float4v __attribute__((ext_vector_type(4)));
typedef unsigned long long u64;

#define NSTEPS 60
#define ROWS   8
#define NWG    256
#define C1S    518
#define WCOPY  65536   // short8 units per weight copy (1 MB); 8 copies in d_ws

// Tsit5 coefficients premultiplied by H = 1/60
constexpr double Hd = 1.0 / 60.0;
constexpr float HA1[1] = { (float)(Hd * 0.161) };
constexpr float HA2[2] = { (float)(Hd * -0.008480655492356989), (float)(Hd * 0.335480655492357) };
constexpr float HA3[3] = { (float)(Hd * 2.8971530571054935), (float)(Hd * -6.359448489975075),
                           (float)(Hd * 4.3622954328695815) };
constexpr float HA4[4] = { (float)(Hd * 5.325864828439257), (float)(Hd * -11.748883564062828),
                           (float)(Hd * 7.4955393428898365), (float)(Hd * -0.09249506636175525) };
constexpr float HA5[5] = { (float)(Hd * 5.86145544294642), (float)(Hd * -12.92096931784711),
                           (float)(Hd * 8.159367898576159), (float)(Hd * -0.071584973281401),
                           (float)(Hd * -0.028269050394068383) };
constexpr float HB6[6] = { (float)(Hd * 0.09646076681806523), (float)(Hd * 0.01),
                           (float)(Hd * 0.4798896504144996), (float)(Hd * 1.379008574103742),
                           (float)(Hd * -3.290069515436081), (float)(Hd * 2.324710524099774) };

__device__ __forceinline__ unsigned short f2bf(float f) {
    union { float f; unsigned u; } v; v.f = f;
    unsigned r = v.u + 0x7fffu + ((v.u >> 16) & 1u);   // RNE
    return (unsigned short)(r >> 16);
}

// f32 row-major -> bf16 fragment-linear blocks, replicated 8x (one copy per XCD).
// Block (nt,ks) = 1 KB; lane l holds W[n=nt*16+(l&15)][k=ks*32+(l>>4)*8 .. +8].
// Copy layout (short8 units): [W1y: 256 blks][W2: 512 blks][W3: 256 blks] = 1 MB.
__global__ void wconv(const float* __restrict__ W1, const float* __restrict__ W2,
                      const float* __restrict__ W3, unsigned short* __restrict__ ws) {
    int g = blockIdx.x * blockDim.x + threadIdx.x;   // 0..65535
    int blk = g >> 6, l = g & 63;
    const float* src;
    if (blk < 256) {                  // W1y: N=512, K=256 (input cols 0..255 of W1)
        int b = blk; int nt = b >> 3, ks = b & 7;
        src = W1 + (nt * 16 + (l & 15)) * 512 + ks * 32 + (l >> 4) * 8;
    } else if (blk < 768) {           // W2: N=512, K=512
        int b = blk - 256; int nt = b >> 4, ks = b & 15;
        src = W2 + (nt * 16 + (l & 15)) * 512 + ks * 32 + (l >> 4) * 8;
    } else {                          // W3: N=256, K=512
        int b = blk - 768; int nt = b >> 4, ks = b & 15;
        src = W3 + (nt * 16 + (l & 15)) * 512 + ks * 32 + (l >> 4) * 8;
    }
    short8 v;
#pragma unroll
    for (int j = 0; j < 8; ++j) v[j] = (short)f2bf(src[j]);
    short8* o = (short8*)ws;
#pragma unroll
    for (int c = 0; c < 8; ++c) o[(size_t)c * WCOPY + g] = v;
}

// A-fragment load: two u64 (ds_read_b64) with 16-value granule-XOR swizzle
// (R5-measured: zero bank conflicts). Row layout [row][RG u64-granules],
// granule g stored at g ^ (row & 15). RG = KDIM/4.
template<int RG>
__device__ __forceinline__ short8 lda(const unsigned short* h, int row, int ks, int l4) {
    const u64* p = (const u64*)h;
    const int base = row * RG, s = row & 15;
    const int g0 = ks * 8 + l4 * 2;
    union { u64 q[2]; short8 v; } t;
    t.q[0] = p[base + (g0 ^ s)];
    t.q[1] = p[base + ((g0 + 1) ^ s)];
    return t.v;
}
// bf16 scalar store into the same swizzled layout.
template<int RG>
__device__ __forceinline__ void sth(unsigned short* h, int row, int n, unsigned short v) {
    h[row * (RG * 4) + (((n >> 2) ^ (row & 15)) << 2) + (n & 3)] = v;
}

// NT output tiles per wave, single pass, b-prefetch-1. acc = NT float4.
template<int KDIM, int NT>
__device__ __forceinline__ void mblk(const unsigned short* __restrict__ lds,
                                     const short8* __restrict__ wb, int ntg0, int lane,
                                     float4v* acc) {
    constexpr int KS = KDIM / 32;
    const int l15 = lane & 15, l4 = lane >> 4;
    const short8* wp = wb + (size_t)ntg0 * KS * 64 + lane;
    short8 bc[NT];
#pragma unroll
    for (int nt = 0; nt < NT; ++nt) bc[nt] = wp[(size_t)nt * KS * 64];
#pragma unroll
    for (int ks = 0; ks < KS; ++ks) {
        short8 a = lda<KDIM / 4>(lds, l15, ks, l4);
        short8 bn[NT];
#pragma unroll
        for (int nt = 0; nt < NT; ++nt)
            bn[nt] = (ks < KS - 1) ? wp[((size_t)nt * KS + ks + 1) * 64] : bc[nt];
#pragma unroll
        for (int nt = 0; nt < NT; ++nt)
            acc[nt] = __builtin_amdgcn_mfma_f32_16x16x32_bf16(a, bc[nt], acc[nt], 0, 0, 0);
#pragma unroll
        for (int nt = 0; nt < NT; ++nt) bc[nt] = bn[nt];
    }
}

// One WG = 8 rows (duplicated to 16 LDS rows for the swizzle + full M=16 MFMA),
// 8 waves, full 60-step integration. k1..k6 and y in registers.
__global__ void __launch_bounds__(512, 2) odeint(
        const float* __restrict__ x0, const float* __restrict__ uf,
        const float* __restrict__ W1, const float* __restrict__ b1,
        const float* __restrict__ b2g, const float* __restrict__ b3g,
        const unsigned short* __restrict__ ws, float* __restrict__ out) {
    __shared__ __align__(16) unsigned short xb[16 * 256];   // 8 KB
    __shared__ __align__(16) unsigned short h1[16 * 512];   // 16 KB
    __shared__ __align__(16) unsigned short h2[16 * 512];   // 16 KB
    __shared__ float c1s[8 * C1S];                          // 16.6 KB

    const int tid = threadIdx.x, w = tid >> 6, lane = tid & 63;
    const int l15 = lane & 15, l4 = lane >> 4;
    const int r0 = blockIdx.x * ROWS;
    const bool forced = (r0 < 1024);

    // Per-XCD private weight copy (blockIdx round-robins across XCDs).
    const short8* base = (const short8*)ws + (size_t)(blockIdx.x & 7) * WCOPY;
    const short8* wy1 = base;              // W1y blocks 0..255
    const short8* w2b = base + 256 * 64;   // W2  blocks 256..767
    const short8* w3b = base + 768 * 64;   // W3  blocks 768..1023

    // ---- stage u (f32) into h1-as-scratch ----
    float* utmp = (float*)h1;              // 8 rows x 256 f32 = 8 KB
    {
        float4v* ud = (float4v*)utmp;
        for (int i = tid; i < ROWS * 64; i += 512) {
            float4v v = {0.f, 0.f, 0.f, 0.f};
            if (forced) v = *(const float4v*)(uf + (size_t)(r0 + (i >> 6)) * 256 + (i & 63) * 4);
            ud[i] = v;
        }
    }
    __syncthreads();

    // ---- c1 = W1u @ u + b1 (one-time, f32 VALU; broadcast LDS reads) ----
    {
        int n = tid;
        float acc8[ROWS];
        float bb = b1[n];
#pragma unroll
        for (int r = 0; r < ROWS; ++r) acc8[r] = bb;
        const float* wrow = W1 + n * 512 + 256;
        for (int k = 0; k < 256; ++k) {
            float wv = wrow[k];
#pragma unroll
            for (int r = 0; r < ROWS; ++r) acc8[r] += wv * utmp[r * 256 + k];
        }
#pragma unroll
        for (int r = 0; r < ROWS; ++r) c1s[r * C1S + n] = acc8[r];
    }
    __syncthreads();                       // utmp dead; h1 free

    // ---- biases to registers ----
    float b2r[4], b3r[2];
#pragma unroll
    for (int j = 0; j < 4; ++j) b2r[j] = b2g[(w * 4 + j) * 16 + l15];
#pragma unroll
    for (int nt = 0; nt < 2; ++nt) b3r[nt] = b3g[(w * 2 + nt) * 16 + l15];

    // ---- y, k in registers; C/D layout: row = l4*4 + r (0..15, 8..15 dup 0..7),
    //      col n = (w*2+nt)*16 + l15; e = nt*4 + r ----
    float ybr[8];
    float kreg[6][8];
#pragma unroll
    for (int e = 0; e < 8; ++e) {
        int nt = e >> 2, r = e & 3;
        int grow = r0 + ((l4 * 4 + r) & 7);
        ybr[e] = x0[(size_t)(grow & 1023) * 256 + (w * 2 + nt) * 16 + l15];
    }

#define DO_STAGE(S, COEF) do {                                                          \
    {   /* stage input x = y + sum_{j<S} COEF[j]*k_j -> xb (16 rows incl dups) */       \
        _Pragma("unroll")                                                               \
        for (int e = 0; e < 8; ++e) {                                                   \
            int nt_ = e >> 2, r_ = e & 3;                                               \
            int row_ = l4 * 4 + r_;                                                     \
            float v_ = ybr[e];                                                          \
            _Pragma("unroll")                                                           \
            for (int j = 0; j < S; ++j) v_ += COEF[j] * kreg[j][e];                     \
            sth<64>(xb, row_, (w * 2 + nt_) * 16 + l15, f2bf(v_));                      \
        }                                                                               \
    }                                                                                   \
    __syncthreads();  /* B1: xb ready */                                                \
    {   /* L1: xb (K=256) @ W1y -> h1 (+c1, relu), NT=4 single pass */                  \
        float4v a1[4] = {{0,0,0,0},{0,0,0,0},{0,0,0,0},{0,0,0,0}};                      \
        mblk<256, 4>(xb, wy1, w * 4, lane, a1);                                         \
        _Pragma("unroll")                                                               \
        for (int j = 0; j < 4; ++j) {                                                   \
            int n_g = (w * 4 + j) * 16 + l15;                                           \
            _Pragma("unroll")                                                           \
            for (int r = 0; r < 4; ++r) {                                               \
                int row = l4 * 4 + r;                                                   \
                float v = a1[j][r] + c1s[(row & 7) * C1S + n_g];                        \
                sth<128>(h1, row, n_g, f2bf(fmaxf(v, 0.f)));                            \
            }                                                                           \
        }                                                                               \
    }                                                                                   \
    __syncthreads();  /* B2: h1 ready */                                                \
    {   /* L2: h1 (K=512) @ W2 -> h2 (+b2, relu), NT=4 single pass */                   \
        float4v a2[4] = {{0,0,0,0},{0,0,0,0},{0,0,0,0},{0,0,0,0}};                      \
        mblk<512, 4>(h1, w2b, w * 4, lane, a2);                                         \
        _Pragma("unroll")                                                               \
        for (int j = 0; j < 4; ++j) {                                                   \
            int n_g = (w * 4 + j) * 16 + l15;                                           \
            _Pragma("unroll")                                                           \
            for (int r = 0; r < 4; ++r) {                                               \
                int row = l4 * 4 + r;                                                   \
                sth<128>(h2, row, n_g, f2bf(fmaxf(a2[j][r] + b2r[j], 0.f)));            \
            }                                                                           \
        }                                                                               \
    }                                                                                   \
    __syncthreads();  /* B3: h2 ready */                                                \
    {   /* L3: h2 (K=512) @ W3 -> kreg[S] (registers), NT=2 */                          \
        float4v a3[2] = {{0,0,0,0},{0,0,0,0}};                                          \
        mblk<512, 2>(h2, w3b, w * 2, lane, a3);                                         \
        _Pragma("unroll")                                                               \
        for (int nt = 0; nt < 2; ++nt)                                                  \
            _Pragma("unroll")                                                           \
            for (int r = 0; r < 4; ++r)                                                 \
                kreg[S][nt * 4 + r] = a3[nt][r] + b3r[nt];                              \
    }                                                                                   \
} while (0)

    for (int step = 0; step < NSTEPS; ++step) {
        DO_STAGE(0, HA1);
        DO_STAGE(1, HA1);
        DO_STAGE(2, HA2);
        DO_STAGE(3, HA3);
        DO_STAGE(4, HA4);
        DO_STAGE(5, HA5);
        {   // y update (registers only; dup rows stay consistent automatically)
#pragma unroll
            for (int e = 0; e < 8; ++e) {
                float v = ybr[e];
#pragma unroll
                for (int j = 0; j < 6; ++j) v += HB6[j] * kreg[j][e];
                ybr[e] = v;
            }
        }
    }
#undef DO_STAGE

#pragma unroll
    for (int e = 0; e < 8; ++e) {
        int nt = e >> 2, r = e & 3;
        int row = l4 * 4 + r;
        if (row < 8)
            out[(size_t)(r0 + row) * 256 + (w * 2 + nt) * 16 + l15] = ybr[e];
    }
}

extern "C" void kernel_launch(void* const* d_in, const int* in_sizes, int n_in,
                              void* d_out, int out_size, void* d_ws, size_t ws_size,
                              hipStream_t stream) {
    const float* x0 = (const float*)d_in[0];
    const float* uf = (const float*)d_in[1];
    const float* W1 = (const float*)d_in[2];
    const float* b1 = (const float*)d_in[3];
    const float* W2 = (const float*)d_in[4];
    const float* b2 = (const float*)d_in[5];
    const float* W3 = (const float*)d_in[6];
    const float* b3 = (const float*)d_in[7];
    unsigned short* ws = (unsigned short*)d_ws;   // 8 MB: 8 per-XCD weight copies

    wconv<<<128, 512, 0, stream>>>(W1, W2, W3, ws);
    odeint<<<NWG, 512, 0, stream>>>(x0, uf, W1, b1, b2, b3, ws, (float*)d_out);
}

// Round 8
// 15578.349 us; speedup vs baseline: 2.1231x; 1.3226x over previous
//
#include <hip/hip_runtime.h>
#include <hip/hip_bf16.h>

typedef short  short8  __attribute__((ext_vector_type(8)));
typedef float  float4v __attribute__((ext_vector_type(4)));
typedef unsigned long long u64;

#define NSTEPS 60
#define ROWS   32
#define NWG    64    // 2048 / 32 rows; 1024-thread WGs (16 waves), 1 WG/CU

// Tsit5 coefficients premultiplied by H = 1/60
constexpr double Hd = 1.0 / 60.0;
constexpr float HA1[1] = { (float)(Hd * 0.161) };
constexpr float HA2[2] = { (float)(Hd * -0.008480655492356989), (float)(Hd * 0.335480655492357) };
constexpr float HA3[3] = { (float)(Hd * 2.8971530571054935), (float)(Hd * -6.359448489975075),
                           (float)(Hd * 4.3622954328695815) };
constexpr float HA4[4] = { (float)(Hd * 5.325864828439257), (float)(Hd * -11.748883564062828),
                           (float)(Hd * 7.4955393428898365), (float)(Hd * -0.09249506636175525) };
constexpr float HA5[5] = { (float)(Hd * 5.86145544294642), (float)(Hd * -12.92096931784711),
                           (float)(Hd * 8.159367898576159), (float)(Hd * -0.071584973281401),
                           (float)(Hd * -0.028269050394068383) };
constexpr float HB6[6] = { (float)(Hd * 0.09646076681806523), (float)(Hd * 0.01),
                           (float)(Hd * 0.4798896504144996), (float)(Hd * 1.379008574103742),
                           (float)(Hd * -3.290069515436081), (float)(Hd * 2.324710524099774) };

__device__ __forceinline__ unsigned short f2bf(float f) {
    union { float f; unsigned u; } v; v.f = f;
    unsigned r = v.u + 0x7fffu + ((v.u >> 16) & 1u);   // RNE
    return (unsigned short)(r >> 16);
}
__device__ __forceinline__ unsigned pack2(float a, float b) {
    return (unsigned)f2bf(a) | ((unsigned)f2bf(b) << 16);
}
__device__ __forceinline__ float bfl(unsigned u) { union { unsigned v; float f; } x; x.v = u << 16;        return x.f; }
__device__ __forceinline__ float bfh(unsigned u) { union { unsigned v; float f; } x; x.v = u & 0xffff0000u; return x.f; }

// f32 row-major -> bf16 fragment-linear 1-KB blocks (single shared copy, 1.25 MB).
// Lane l of block (nt,ks) holds W[n=nt*16+(l&15)][k=ks*32+(l>>4)*8 .. +8].
// short8-block layout: [W1y: 256][W2: 512][W3: 256][W1u: 256] (blk = 64 short8).
__global__ void wconv(const float* __restrict__ W1, const float* __restrict__ W2,
                      const float* __restrict__ W3, unsigned short* __restrict__ ws) {
    int g = blockIdx.x * blockDim.x + threadIdx.x;   // 0..81919
    int blk = g >> 6, l = g & 63;
    const float* src;
    if (blk < 256) {                  // W1y: K-cols 0..255 of W1
        int nt = blk >> 3, ks = blk & 7;
        src = W1 + (nt * 16 + (l & 15)) * 512 + ks * 32 + (l >> 4) * 8;
    } else if (blk < 768) {           // W2
        int b = blk - 256; int nt = b >> 4, ks = b & 15;
        src = W2 + (nt * 16 + (l & 15)) * 512 + ks * 32 + (l >> 4) * 8;
    } else if (blk < 1024) {          // W3
        int b = blk - 768; int nt = b >> 4, ks = b & 15;
        src = W3 + (nt * 16 + (l & 15)) * 512 + ks * 32 + (l >> 4) * 8;
    } else {                          // W1u: K-cols 256..511 of W1
        int b = blk - 1024; int nt = b >> 3, ks = b & 7;
        src = W1 + (nt * 16 + (l & 15)) * 512 + ks * 32 + (l >> 4) * 8 + 256;
    }
    short8 v;
#pragma unroll
    for (int j = 0; j < 8; ++j) v[j] = (short)f2bf(src[j]);
    *(((short8*)ws) + g) = v;
}

// A-fragment load: two ds_read_b64 with 16-granule XOR swizzle (R5-measured: 0 conflicts).
// Row layout [row][RG u64-granules]; granule g stored at g ^ (row & 15).
template<int RG>
__device__ __forceinline__ short8 lda(const unsigned short* h, int row, int ks, int l4) {
    const u64* p = (const u64*)h;
    const int base = row * RG, s = row & 15;
    const int g0 = ks * 8 + l4 * 2;
    union { u64 q[2]; short8 v; } t;
    t.q[0] = p[base + (g0 ^ s)];
    t.q[1] = p[base + ((g0 + 1) ^ s)];
    return t.v;
}
// bf16 scalar store into the same swizzled layout.
template<int RG>
__device__ __forceinline__ void sth(unsigned short* h, int row, int n, unsigned short v) {
    h[row * (RG * 4) + (((n >> 2) ^ (row & 15)) << 2) + (n & 3)] = v;
}

// Two M-tiles (rows l15 and 16+l15) x NTJ N-tiles, B-prefetch-1.
template<int KDIM, int NTJ>
__device__ __forceinline__ void mblk2(const unsigned short* __restrict__ lds,
                                      const short8* __restrict__ wb, int ntg0, int lane,
                                      float4v (&acc)[NTJ][2]) {
    constexpr int KS = KDIM / 32;
    const int l15 = lane & 15, l4 = lane >> 4;
    const short8* wp = wb + (size_t)ntg0 * KS * 64 + lane;
    short8 bc[NTJ];
#pragma unroll
    for (int j = 0; j < NTJ; ++j) bc[j] = wp[(size_t)j * KS * 64];
#pragma unroll
    for (int ks = 0; ks < KS; ++ks) {
        short8 a0 = lda<KDIM / 4>(lds, l15,      ks, l4);
        short8 a1 = lda<KDIM / 4>(lds, 16 + l15, ks, l4);
        short8 bn[NTJ];
#pragma unroll
        for (int j = 0; j < NTJ; ++j)
            bn[j] = (ks < KS - 1) ? wp[((size_t)j * KS + ks + 1) * 64] : bc[j];
#pragma unroll
        for (int j = 0; j < NTJ; ++j) {
            acc[j][0] = __builtin_amdgcn_mfma_f32_16x16x32_bf16(a0, bc[j], acc[j][0], 0, 0, 0);
            acc[j][1] = __builtin_amdgcn_mfma_f32_16x16x32_bf16(a1, bc[j], acc[j][1], 0, 0, 0);
        }
#pragma unroll
        for (int j = 0; j < NTJ; ++j) bc[j] = bn[j];
    }
}

// One WG = 32 rows, 16 waves (1024 thr), full 60-step Tsit5. y,k,c1 in registers.
__global__ void __launch_bounds__(1024, 4) odeint(
        const float* __restrict__ x0, const float* __restrict__ uf,
        const float* __restrict__ b1g, const float* __restrict__ b2g,
        const float* __restrict__ b3g, const unsigned short* __restrict__ ws,
        float* __restrict__ out) {
    __shared__ __align__(16) unsigned short xb[32 * 256];   // 16 KB
    __shared__ __align__(16) unsigned short h1[32 * 512];   // 32 KB
    __shared__ __align__(16) unsigned short h2[32 * 512];   // 32 KB

    const int tid = threadIdx.x, w = tid >> 6, lane = tid & 63;
    const int l15 = lane & 15, l4 = lane >> 4;
    const int r0 = blockIdx.x * ROWS;
    const bool forced = (r0 < 1024);

    const short8* ws8 = (const short8*)ws;
    const short8* wy1 = ws8;               // W1y
    const short8* w2b = ws8 + 256 * 64;    // W2
    const short8* w3b = ws8 + 768 * 64;    // W3
    const short8* wub = ws8 + 1024 * 64;   // W1u

    // ---- stage u (bf16, swizzled) straight into xb ----
    {
        u64* xq = (u64*)xb;
        for (int i = tid; i < 32 * 64; i += 1024) {
            int row = i >> 6, g = i & 63;
            union { u64 q; unsigned short s[4]; } t;
            t.q = 0;
            if (forced) {
                const float* up = uf + (size_t)(r0 + row) * 256 + g * 4;
#pragma unroll
                for (int e = 0; e < 4; ++e) t.s[e] = f2bf(up[e]);
            }
            xq[row * 64 + (g ^ (row & 15))] = t.q;
        }
    }
    __syncthreads();

    // ---- biases to registers ----
    float b2r[2];
#pragma unroll
    for (int j = 0; j < 2; ++j) b2r[j] = b2g[(w * 2 + j) * 16 + l15];
    const float b3r = b3g[w * 16 + l15];

    // ---- c1 = u @ W1u^T + b1 (one-time MFMA), packed bf16: c1p[j][mt][hi/lo pair] ----
    unsigned c1p[2][2][2];
    {
        float4v acc[2][2];
#pragma unroll
        for (int j = 0; j < 2; ++j)
#pragma unroll
        for (int mt = 0; mt < 2; ++mt) acc[j][mt] = (float4v){0.f, 0.f, 0.f, 0.f};
        mblk2<256, 2>(xb, wub, w * 2, lane, acc);
#pragma unroll
        for (int j = 0; j < 2; ++j) {
            float bb = b1g[(w * 2 + j) * 16 + l15];
#pragma unroll
            for (int mt = 0; mt < 2; ++mt) {
                c1p[j][mt][0] = pack2(acc[j][mt][0] + bb, acc[j][mt][1] + bb);
                c1p[j][mt][1] = pack2(acc[j][mt][2] + bb, acc[j][mt][3] + bb);
            }
        }
    }
    __syncthreads();                        // xb consumed; free for stage inputs

    // ---- y, k in registers; e = mt*4 + r: row = mt*16 + l4*4 + r, col = w*16 + l15 ----
    float ybr[8];
    float kreg[6][8];
#pragma unroll
    for (int e = 0; e < 8; ++e) {
        int mt = e >> 2, r = e & 3;
        int row = mt * 16 + l4 * 4 + r;
        ybr[e] = x0[(size_t)((r0 + row) & 1023) * 256 + w * 16 + l15];
    }

#define DO_STAGE(S, COEF) do {                                                          \
    {   /* stage input x = y + sum_{j<S} COEF[j]*k_j -> xb (own col slice) */           \
        _Pragma("unroll")                                                               \
        for (int e = 0; e < 8; ++e) {                                                   \
            int mt_ = e >> 2, r_ = e & 3;                                               \
            float v_ = ybr[e];                                                          \
            _Pragma("unroll")                                                           \
            for (int j = 0; j < S; ++j) v_ += COEF[j] * kreg[j][e];                     \
            sth<64>(xb, mt_ * 16 + l4 * 4 + r_, w * 16 + l15, f2bf(v_));                \
        }                                                                               \
    }                                                                                   \
    __syncthreads();  /* B1: xb ready */                                                \
    {   /* L1: xb (K=256) @ W1y -> h1 (+c1, relu) */                                    \
        float4v a1[2][2];                                                               \
        _Pragma("unroll") for (int j = 0; j < 2; ++j)                                   \
        _Pragma("unroll") for (int mt = 0; mt < 2; ++mt) a1[j][mt] = (float4v){0,0,0,0};\
        mblk2<256, 2>(xb, wy1, w * 2, lane, a1);                                        \
        _Pragma("unroll")                                                               \
        for (int j = 0; j < 2; ++j) {                                                   \
            int n_g = (w * 2 + j) * 16 + l15;                                           \
            _Pragma("unroll")                                                           \
            for (int mt = 0; mt < 2; ++mt) {                                            \
                float c0 = bfl(c1p[j][mt][0]), c1v = bfh(c1p[j][mt][0]);                \
                float c2 = bfl(c1p[j][mt][1]), c3 = bfh(c1p[j][mt][1]);                 \
                int rb = mt * 16 + l4 * 4;                                              \
                sth<128>(h1, rb + 0, n_g, f2bf(fmaxf(a1[j][mt][0] + c0, 0.f)));         \
                sth<128>(h1, rb + 1, n_g, f2bf(fmaxf(a1[j][mt][1] + c1v, 0.f)));        \
                sth<128>(h1, rb + 2, n_g, f2bf(fmaxf(a1[j][mt][2] + c2, 0.f)));         \
                sth<128>(h1, rb + 3, n_g, f2bf(fmaxf(a1[j][mt][3] + c3, 0.f)));         \
            }                                                                           \
        }                                                                               \
    }                                                                                   \
    __syncthreads();  /* B2: h1 ready */                                                \
    {   /* L2: h1 (K=512) @ W2 -> h2 (+b2, relu) */                                     \
        float4v a2[2][2];                                                               \
        _Pragma("unroll") for (int j = 0; j < 2; ++j)                                   \
        _Pragma("unroll") for (int mt = 0; mt < 2; ++mt) a2[j][mt] = (float4v){0,0,0,0};\
        mblk2<512, 2>(h1, w2b, w * 2, lane, a2);                                        \
        _Pragma("unroll")                                                               \
        for (int j = 0; j < 2; ++j) {                                                   \
            int n_g = (w * 2 + j) * 16 + l15;                                           \
            _Pragma("unroll")                                                           \
            for (int mt = 0; mt < 2; ++mt) {                                            \
                int rb = mt * 16 + l4 * 4;                                              \
                _Pragma("unroll")                                                       \
                for (int r = 0; r < 4; ++r)                                             \
                    sth<128>(h2, rb + r, n_g, f2bf(fmaxf(a2[j][mt][r] + b2r[j], 0.f))); \
            }                                                                           \
        }                                                                               \
    }                                                                                   \
    __syncthreads();  /* B3: h2 ready */                                                \
    {   /* L3: h2 (K=512) @ W3 -> kreg[S] (registers) */                                \
        float4v a3[1][2];                                                               \
        a3[0][0] = (float4v){0,0,0,0}; a3[0][1] = (float4v){0,0,0,0};                   \
        mblk2<512, 1>(h2, w3b, w, lane, a3);                                            \
        _Pragma("unroll")                                                               \
        for (int mt = 0; mt < 2; ++mt)                                                  \
            _Pragma("unroll")                                                           \
            for (int r = 0; r < 4; ++r)                                                 \
                kreg[S][mt * 4 + r] = a3[0][mt][r] + b3r;                               \
    }                                                                                   \
} while (0)

    for (int step = 0; step < NSTEPS; ++step) {
        DO_STAGE(0, HA1);
        DO_STAGE(1, HA1);
        DO_STAGE(2, HA2);
        DO_STAGE(3, HA3);
        DO_STAGE(4, HA4);
        DO_STAGE(5, HA5);
        {   // y update (pure registers)
#pragma unroll
            for (int e = 0; e < 8; ++e) {
                float v = ybr[e];
#pragma unroll
                for (int j = 0; j < 6; ++j) v += HB6[j] * kreg[j][e];
                ybr[e] = v;
            }
        }
    }
#undef DO_STAGE

#pragma unroll
    for (int e = 0; e < 8; ++e) {
        int mt = e >> 2, r = e & 3;
        int row = mt * 16 + l4 * 4 + r;
        out[(size_t)(r0 + row) * 256 + w * 16 + l15] = ybr[e];
    }
}

extern "C" void kernel_launch(void* const* d_in, const int* in_sizes, int n_in,
                              void* d_out, int out_size, void* d_ws, size_t ws_size,
                              hipStream_t stream) {
    const float* x0 = (const float*)d_in[0];
    const float* uf = (const float*)d_in[1];
    const float* W1 = (const float*)d_in[2];
    const float* b1 = (const float*)d_in[3];
    const float* W2 = (const float*)d_in[4];
    const float* b2 = (const float*)d_in[5];
    const float* W3 = (const float*)d_in[6];
    const float* b3 = (const float*)d_in[7];
    unsigned short* ws = (unsigned short*)d_ws;   // 1.25 MB bf16 weights (shared copy)

    wconv<<<160, 512, 0, stream>>>(W1, W2, W3, ws);
    odeint<<<NWG, 1024, 0, stream>>>(x0, uf, b1, b2, b3, ws, (float*)d_out);
}

// Round 9
// 13371.240 us; speedup vs baseline: 2.4735x; 1.1651x over previous
//
#include <hip/hip_runtime.h>
#include <hip/hip_bf16.h>

typedef short  short8  __attribute__((ext_vector_type(8)));
typedef float  float4v __attribute__((ext_vector_type(4)));
typedef unsigned long long u64;

#define NSTEPS 60
#define ROWS   32
#define NWG    64     // 2048 / 32 rows; 1024-thread WGs (16 waves)
#define WBLKS  1280   // 1-KB fragment blocks per weight copy (1.25 MB)
#define WSTR   (WBLKS * 64)   // short8 units per copy

// Tsit5 coefficients premultiplied by H = 1/60
constexpr double Hd = 1.0 / 60.0;
constexpr float HA1[1] = { (float)(Hd * 0.161) };
constexpr float HA2[2] = { (float)(Hd * -0.008480655492356989), (float)(Hd * 0.335480655492357) };
constexpr float HA3[3] = { (float)(Hd * 2.8971530571054935), (float)(Hd * -6.359448489975075),
                           (float)(Hd * 4.3622954328695815) };
constexpr float HA4[4] = { (float)(Hd * 5.325864828439257), (float)(Hd * -11.748883564062828),
                           (float)(Hd * 7.4955393428898365), (float)(Hd * -0.09249506636175525) };
constexpr float HA5[5] = { (float)(Hd * 5.86145544294642), (float)(Hd * -12.92096931784711),
                           (float)(Hd * 8.159367898576159), (float)(Hd * -0.071584973281401),
                           (float)(Hd * -0.028269050394068383) };
constexpr float HB6[6] = { (float)(Hd * 0.09646076681806523), (float)(Hd * 0.01),
                           (float)(Hd * 0.4798896504144996), (float)(Hd * 1.379008574103742),
                           (float)(Hd * -3.290069515436081), (float)(Hd * 2.324710524099774) };

__device__ __forceinline__ unsigned short f2bf(float f) {
    union { float f; unsigned u; } v; v.f = f;
    unsigned r = v.u + 0x7fffu + ((v.u >> 16) & 1u);   // RNE
    return (unsigned short)(r >> 16);
}
__device__ __forceinline__ unsigned pack2(float a, float b) {
    return (unsigned)f2bf(a) | ((unsigned)f2bf(b) << 16);
}
__device__ __forceinline__ float bfl(unsigned u) { union { unsigned v; float f; } x; x.v = u << 16;        return x.f; }
__device__ __forceinline__ float bfh(unsigned u) { union { unsigned v; float f; } x; x.v = u & 0xffff0000u; return x.f; }

// A-fragment load: two ds_read_b64 with 16-granule XOR swizzle (R5-measured: 0 conflicts).
// Row layout [row][RG u64-granules]; granule g stored at g ^ (row & 15).
template<int RG>
__device__ __forceinline__ short8 lda(const unsigned short* h, int row, int ks, int l4) {
    const u64* p = (const u64*)h;
    const int base = row * RG, s = row & 15;
    const int g0 = ks * 8 + l4 * 2;
    union { u64 q[2]; short8 v; } t;
    t.q[0] = p[base + (g0 ^ s)];
    t.q[1] = p[base + ((g0 + 1) ^ s)];
    return t.v;
}
// bf16 scalar store into the same swizzled layout.
template<int RG>
__device__ __forceinline__ void sth(unsigned short* h, int row, int n, unsigned short v) {
    h[row * (RG * 4) + (((n >> 2) ^ (row & 15)) << 2) + (n & 3)] = v;
}

// Two M-tiles (rows l15 and 16+l15) x NTJ N-tiles, B-prefetch-1.
template<int KDIM, int NTJ>
__device__ __forceinline__ void mblk2(const unsigned short* __restrict__ lds,
                                      const short8* __restrict__ wb, int ntg0, int lane,
                                      float4v (&acc)[NTJ][2]) {
    constexpr int KS = KDIM / 32;
    const int l15 = lane & 15, l4 = lane >> 4;
    const short8* wp = wb + (size_t)ntg0 * KS * 64 + lane;
    short8 bc[NTJ];
#pragma unroll
    for (int j = 0; j < NTJ; ++j) bc[j] = wp[(size_t)j * KS * 64];
#pragma unroll
    for (int ks = 0; ks < KS; ++ks) {
        short8 a0 = lda<KDIM / 4>(lds, l15,      ks, l4);
        short8 a1 = lda<KDIM / 4>(lds, 16 + l15, ks, l4);
        short8 bn[NTJ];
#pragma unroll
        for (int j = 0; j < NTJ; ++j)
            bn[j] = (ks < KS - 1) ? wp[((size_t)j * KS + ks + 1) * 64] : bc[j];
#pragma unroll
        for (int j = 0; j < NTJ; ++j) {
            acc[j][0] = __builtin_amdgcn_mfma_f32_16x16x32_bf16(a0, bc[j], acc[j][0], 0, 0, 0);
            acc[j][1] = __builtin_amdgcn_mfma_f32_16x16x32_bf16(a1, bc[j], acc[j][1], 0, 0, 0);
        }
#pragma unroll
        for (int j = 0; j < NTJ; ++j) bc[j] = bn[j];
    }
}

// One WG = 32 rows, 16 waves, full 60-step Tsit5. y,k,c1 in registers.
// Weight copy is written BY THIS KERNEL into a per-XCD region (dirty L2 lines).
__global__ void __launch_bounds__(1024, 4) odeint(
        const float* __restrict__ x0, const float* __restrict__ uf,
        const float* __restrict__ W1, const float* __restrict__ b1g,
        const float* __restrict__ W2, const float* __restrict__ b2g,
        const float* __restrict__ W3, const float* __restrict__ b3g,
        unsigned short* __restrict__ ws, float* __restrict__ out) {
    __shared__ __align__(16) unsigned short xb[32 * 256];   // 16 KB
    __shared__ __align__(16) unsigned short h1[32 * 512];   // 32 KB
    __shared__ __align__(16) unsigned short h2[32 * 512];   // 32 KB

    const int tid = threadIdx.x, w = tid >> 6, lane = tid & 63;
    const int l15 = lane & 15, l4 = lane >> 4;
    const int r0 = blockIdx.x * ROWS;
    const bool forced = (r0 < 1024);

    // ---- in-kernel per-XCD weight conversion/copy (all 8 WGs of an XCD write
    //      the same bytes redundantly -> no sync needed; lines end up DIRTY in
    //      the local L2 and cannot be silently dropped) ----
    unsigned short* wsc = ws + (size_t)(blockIdx.x & 7) * (WSTR * 8);
    {
        short8* dst = (short8*)wsc;
        for (int g = tid; g < WBLKS * 64; g += 1024) {
            int blk = g >> 6, l = g & 63;
            const float* src;
            if (blk < 256) {                  // W1y: K-cols 0..255 of W1
                int nt = blk >> 3, ks = blk & 7;
                src = W1 + (nt * 16 + (l & 15)) * 512 + ks * 32 + (l >> 4) * 8;
            } else if (blk < 768) {           // W2
                int b = blk - 256; int nt = b >> 4, ks = b & 15;
                src = W2 + (nt * 16 + (l & 15)) * 512 + ks * 32 + (l >> 4) * 8;
            } else if (blk < 1024) {          // W3
                int b = blk - 768; int nt = b >> 4, ks = b & 15;
                src = W3 + (nt * 16 + (l & 15)) * 512 + ks * 32 + (l >> 4) * 8;
            } else {                          // W1u: K-cols 256..511 of W1
                int b = blk - 1024; int nt = b >> 3, ks = b & 7;
                src = W1 + (nt * 16 + (l & 15)) * 512 + ks * 32 + (l >> 4) * 8 + 256;
            }
            short8 v;
#pragma unroll
            for (int j = 0; j < 8; ++j) v[j] = (short)f2bf(src[j]);
            dst[g] = v;
        }
    }

    const short8* ws8 = (const short8*)wsc;
    const short8* wy1 = ws8;               // W1y
    const short8* w2b = ws8 + 256 * 64;    // W2
    const short8* w3b = ws8 + 768 * 64;    // W3
    const short8* wub = ws8 + 1024 * 64;   // W1u

    // ---- stage u (bf16, swizzled) straight into xb ----
    {
        u64* xq = (u64*)xb;
        for (int i = tid; i < 32 * 64; i += 1024) {
            int row = i >> 6, g = i & 63;
            union { u64 q; unsigned short s[4]; } t;
            t.q = 0;
            if (forced) {
                const float* up = uf + (size_t)(r0 + row) * 256 + g * 4;
#pragma unroll
                for (int e = 0; e < 4; ++e) t.s[e] = f2bf(up[e]);
            }
            xq[row * 64 + (g ^ (row & 15))] = t.q;
        }
    }
    __syncthreads();   // copy writes drained (vmcnt) + xb visible

    // ---- biases to registers ----
    float b2r[2];
#pragma unroll
    for (int j = 0; j < 2; ++j) b2r[j] = b2g[(w * 2 + j) * 16 + l15];
    const float b3r = b3g[w * 16 + l15];

    // ---- c1 = u @ W1u^T + b1 (one-time MFMA), packed bf16: c1p[j][mt][pair] ----
    unsigned c1p[2][2][2];
    {
        float4v acc[2][2];
#pragma unroll
        for (int j = 0; j < 2; ++j)
#pragma unroll
        for (int mt = 0; mt < 2; ++mt) acc[j][mt] = (float4v){0.f, 0.f, 0.f, 0.f};
        mblk2<256, 2>(xb, wub, w * 2, lane, acc);
#pragma unroll
        for (int j = 0; j < 2; ++j) {
            float bb = b1g[(w * 2 + j) * 16 + l15];
#pragma unroll
            for (int mt = 0; mt < 2; ++mt) {
                c1p[j][mt][0] = pack2(acc[j][mt][0] + bb, acc[j][mt][1] + bb);
                c1p[j][mt][1] = pack2(acc[j][mt][2] + bb, acc[j][mt][3] + bb);
            }
        }
    }
    __syncthreads();                        // xb consumed; free for stage inputs

    // ---- y, k in registers; e = mt*4 + r: row = mt*16 + l4*4 + r, col = w*16 + l15 ----
    float ybr[8];
    float kreg[6][8];
#pragma unroll
    for (int e = 0; e < 8; ++e) {
        int mt = e >> 2, r = e & 3;
        int row = mt * 16 + l4 * 4 + r;
        ybr[e] = x0[(size_t)((r0 + row) & 1023) * 256 + w * 16 + l15];
    }

#define DO_STAGE(S, COEF) do {                                                          \
    {   /* stage input x = y + sum_{j<S} COEF[j]*k_j -> xb (own col slice) */           \
        _Pragma("unroll")                                                               \
        for (int e = 0; e < 8; ++e) {                                                   \
            int mt_ = e >> 2, r_ = e & 3;                                               \
            float v_ = ybr[e];                                                          \
            _Pragma("unroll")                                                           \
            for (int j = 0; j < S; ++j) v_ += COEF[j] * kreg[j][e];                     \
            sth<64>(xb, mt_ * 16 + l4 * 4 + r_, w * 16 + l15, f2bf(v_));                \
        }                                                                               \
    }                                                                                   \
    __syncthreads();  /* B1: xb ready */                                                \
    {   /* L1: xb (K=256) @ W1y -> h1 (+c1, relu) */                                    \
        float4v a1[2][2];                                                               \
        _Pragma("unroll") for (int j = 0; j < 2; ++j)                                   \
        _Pragma("unroll") for (int mt = 0; mt < 2; ++mt) a1[j][mt] = (float4v){0,0,0,0};\
        mblk2<256, 2>(xb, wy1, w * 2, lane, a1);                                        \
        _Pragma("unroll")                                                               \
        for (int j = 0; j < 2; ++j) {                                                   \
            int n_g = (w * 2 + j) * 16 + l15;                                           \
            _Pragma("unroll")                                                           \
            for (int mt = 0; mt < 2; ++mt) {                                            \
                float c0 = bfl(c1p[j][mt][0]), c1v = bfh(c1p[j][mt][0]);                \
                float c2 = bfl(c1p[j][mt][1]), c3 = bfh(c1p[j][mt][1]);                 \
                int rb = mt * 16 + l4 * 4;                                              \
                sth<128>(h1, rb + 0, n_g, f2bf(fmaxf(a1[j][mt][0] + c0, 0.f)));         \
                sth<128>(h1, rb + 1, n_g, f2bf(fmaxf(a1[j][mt][1] + c1v, 0.f)));        \
                sth<128>(h1, rb + 2, n_g, f2bf(fmaxf(a1[j][mt][2] + c2, 0.f)));         \
                sth<128>(h1, rb + 3, n_g, f2bf(fmaxf(a1[j][mt][3] + c3, 0.f)));         \
            }                                                                           \
        }                                                                               \
    }                                                                                   \
    __syncthreads();  /* B2: h1 ready */                                                \
    {   /* L2: h1 (K=512) @ W2 -> h2 (+b2, relu) */                                     \
        float4v a2[2][2];                                                               \
        _Pragma("unroll") for (int j = 0; j < 2; ++j)                                   \
        _Pragma("unroll") for (int mt = 0; mt < 2; ++mt) a2[j][mt] = (float4v){0,0,0,0};\
        mblk2<512, 2>(h1, w2b, w * 2, lane, a2);                                        \
        _Pragma("unroll")                                                               \
        for (int j = 0; j < 2; ++j) {                                                   \
            int n_g = (w * 2 + j) * 16 + l15;                                           \
            _Pragma("unroll")                                                           \
            for (int mt = 0; mt < 2; ++mt) {                                            \
                int rb = mt * 16 + l4 * 4;                                              \
                _Pragma("unroll")                                                       \
                for (int r = 0; r < 4; ++r)                                             \
                    sth<128>(h2, rb + r, n_g, f2bf(fmaxf(a2[j][mt][r] + b2r[j], 0.f))); \
            }                                                                           \
        }                                                                               \
    }                                                                                   \
    __syncthreads();  /* B3: h2 ready */                                                \
    {   /* L3: h2 (K=512) @ W3 -> kreg[S] (registers) */                                \
        float4v a3[1][2];                                                               \
        a3[0][0] = (float4v){0,0,0,0}; a3[0][1] = (float4v){0,0,0,0};                   \
        mblk2<512, 1>(h2, w3b, w, lane, a3);                                            \
        _Pragma("unroll")                                                               \
        for (int mt = 0; mt < 2; ++mt)                                                  \
            _Pragma("unroll")                                                           \
            for (int r = 0; r < 4; ++r)                                                 \
                kreg[S][mt * 4 + r] = a3[0][mt][r] + b3r;                               \
    }                                                                                   \
} while (0)

    for (int step = 0; step < NSTEPS; ++step) {
        DO_STAGE(0, HA1);
        DO_STAGE(1, HA1);
        DO_STAGE(2, HA2);
        DO_STAGE(3, HA3);
        DO_STAGE(4, HA4);
        DO_STAGE(5, HA5);
        {   // y update (pure registers)
#pragma unroll
            for (int e = 0; e < 8; ++e) {
                float v = ybr[e];
#pragma unroll
                for (int j = 0; j < 6; ++j) v += HB6[j] * kreg[j][e];
                ybr[e] = v;
            }
        }
    }
#undef DO_STAGE

#pragma unroll
    for (int e = 0; e < 8; ++e) {
        int mt = e >> 2, r = e & 3;
        int row = mt * 16 + l4 * 4 + r;
        out[(size_t)(r0 + row) * 256 + w * 16 + l15] = ybr[e];
    }
}

extern "C" void kernel_launch(void* const* d_in, const int* in_sizes, int n_in,
                              void* d_out, int out_size, void* d_ws, size_t ws_size,
                              hipStream_t stream) {
    const float* x0 = (const float*)d_in[0];
    const float* uf = (const float*)d_in[1];
    const float* W1 = (const float*)d_in[2];
    const float* b1 = (const float*)d_in[3];
    const float* W2 = (const float*)d_in[4];
    const float* b2 = (const float*)d_in[5];
    const float* W3 = (const float*)d_in[6];
    const float* b3 = (const float*)d_in[7];
    unsigned short* ws = (unsigned short*)d_ws;   // 10 MB: 8 per-XCD weight copies

    odeint<<<NWG, 1024, 0, stream>>>(x0, uf, W1, b1, W2, b2, W3, b3, ws, (float*)d_out);
}